// Round 8
// baseline (428.815 us; speedup 1.0000x reference)
//
#include <hip/hip_runtime.h>
#include <hip/hip_bf16.h>

#define H_IN 256
#define H    128
#define BN_EPS 1e-5f
#define NCOPY 32
#define NSLICE 256   // edge slices for radix pipeline
#define SMAX 5120    // sortb LDS staging capacity (max bucket ~4400)

using u16 = unsigned short;
using u32 = unsigned int;
typedef __attribute__((ext_vector_type(8))) unsigned short us8;
typedef __attribute__((ext_vector_type(8))) short bf16x8;
typedef __attribute__((ext_vector_type(4))) float f32x4;

__device__ __forceinline__ float b2f(u16 u) {
    return __uint_as_float(((u32)u) << 16);
}
__device__ __forceinline__ u16 f2b(float f) {  // round-to-nearest-even
    u32 u = __float_as_uint(f);
    u += 0x7FFF + ((u >> 16) & 1);
    return (u16)(u >> 16);
}

// ---------------- radix pass 1: LDS row-histogram halves + coarse col-bucket counts ----------------
// grid = 2*NSLICE blocks; block b: slice = b>>1, half = b&1.
// dynamic LDS: hist[hwords] (u16-packed pairs for nodes [half*halfN, half*halfN+halfN)) + bcnt[256]
__global__ __launch_bounds__(256) void radix1_k(const int* __restrict__ row,
                                                const int* __restrict__ col,
                                                u32* __restrict__ hist_part,
                                                u32* __restrict__ bcnt_part,
                                                int E, int halfN, int hwords) {
    extern __shared__ u32 lds[];
    u32* hist = lds;
    u32* bcnt = lds + hwords;
    int tid = threadIdx.x;
    int slice = blockIdx.x >> 1;
    int half = blockIdx.x & 1;
    for (int i = tid; i < hwords; i += 256) hist[i] = 0;
    bcnt[tid] = 0;
    __syncthreads();

    int len = (E + NSLICE - 1) / NSLICE;
    int e0 = slice * len;
    int e1 = min(e0 + len, E);
    int lo = half * halfN;
    for (int e = e0 + tid; e < e1; e += 256) {
        int r = row[e] - lo;
        if ((u32)r < (u32)halfN)
            atomicAdd(&hist[r >> 1], 1u << ((r & 1) << 4));
        if (half == 0) atomicAdd(&bcnt[((u32)col[e]) >> 8], 1u);
    }
    __syncthreads();
    u32* hdst = hist_part + (size_t)blockIdx.x * hwords;
    for (int i = tid; i < hwords; i += 256) hdst[i] = hist[i];
    if (half == 0) bcnt_part[slice * 256 + tid] = bcnt[tid];
}

// ---------------- scan bucket counts -> per-(slice,bucket) offsets + bucket bases ----------------
__global__ void scanb_k(const u32* __restrict__ bcnt_part, u32* __restrict__ boff,
                        u32* __restrict__ bbase) {
    __shared__ u32 sh[256];
    int k = threadIdx.x;
    u32 s = 0;
    for (int b = 0; b < NSLICE; ++b) {
        u32 t = bcnt_part[b * 256 + k];
        boff[b * 256 + k] = s;
        s += t;
    }
    u32 own = s;
    sh[k] = s;
    __syncthreads();
    for (int o = 1; o < 256; o <<= 1) {
        u32 t = (k >= o) ? sh[k - o] : 0;
        __syncthreads();
        sh[k] += t;
        __syncthreads();
    }
    u32 base = sh[k] - own;
    bbase[k] = base;
    if (k == 255) bbase[256] = sh[255];  // == E
    for (int b = 0; b < NSLICE; ++b) boff[b * 256 + k] += base;
}

// ---------------- reduce histogram partials -> dinv ----------------
// hist_part layout: [slice*2+half][hwords]
__global__ void dinv2_k(const u32* __restrict__ hist_part, float* __restrict__ dinv,
                        int N, int halfN, int hwords) {
    int w = blockIdx.x * blockDim.x + threadIdx.x;   // word in [0, 2*hwords)
    if (w >= 2 * hwords) return;
    int h = (w >= hwords) ? 1 : 0;
    int lw = w - h * hwords;
    u32 v = 0;
    for (int s = 0; s < NSLICE; ++s) v += hist_part[(size_t)(s * 2 + h) * hwords + lw];
    int n = h * halfN + 2 * lw;
    if (n < N)     dinv[n]     = rsqrtf((float)(v & 0xFFFF) + 1.0f);
    if (n + 1 < N) dinv[n + 1] = rsqrtf((float)(v >> 16) + 1.0f);
}

// ---------------- scatter edges into coarse buckets (LDS cursors) ----------------
// grid = NSLICE blocks. Edge record: row (16b low) | col&255 (bits 16..23)
__global__ __launch_bounds__(256) void scat2_k(const int* __restrict__ row,
                                               const int* __restrict__ col,
                                               const u32* __restrict__ boff,
                                               u32* __restrict__ ebuf, int E) {
    __shared__ u32 cur[256];
    int tid = threadIdx.x;
    int slice = blockIdx.x;
    cur[tid] = boff[slice * 256 + tid];
    __syncthreads();
    int len = (E + NSLICE - 1) / NSLICE;
    int e0 = slice * len;
    int e1 = min(e0 + len, E);
    for (int e = e0 + tid; e < e1; e += 256) {
        u32 r = (u32)row[e];
        u32 c = (u32)col[e];
        u32 pos = atomicAdd(&cur[c >> 8], 1u);
        ebuf[pos] = r | ((c & 255u) << 16);
    }
}

// ---------------- per-bucket LDS counting sort -> exact CSR (esrc as u16) ----------------
// grid = NB buckets; bucket b covers nodes [256b, 256b+256)
__global__ __launch_bounds__(256) void sortb_k(const u32* __restrict__ ebuf,
                                               const u32* __restrict__ bbase,
                                               int* __restrict__ rowptr,
                                               u16* __restrict__ esrc, int N) {
    __shared__ u32 est[SMAX];
    __shared__ u32 hist[256], scanv[256], cur[256];
    int b = blockIdx.x, tid = threadIdx.x;
    u32 base = bbase[b];
    int size = (int)(bbase[b + 1] - base);
    int st = min(size, SMAX);
    hist[tid] = 0;
    __syncthreads();
    for (int i = tid; i < st; i += 256) {
        u32 e = ebuf[base + i];
        est[i] = e;
        atomicAdd(&hist[(e >> 16) & 255u], 1u);
    }
    for (int i = SMAX + tid; i < size; i += 256) {
        u32 e = ebuf[base + i];
        atomicAdd(&hist[(e >> 16) & 255u], 1u);
    }
    __syncthreads();
    u32 own = hist[tid];
    scanv[tid] = own;
    __syncthreads();
    for (int o = 1; o < 256; o <<= 1) {
        u32 t = (tid >= o) ? scanv[tid - o] : 0;
        __syncthreads();
        scanv[tid] += t;
        __syncthreads();
    }
    u32 excl = scanv[tid] - own;
    int idx = (b << 8) + tid;
    if (idx <= N) rowptr[idx] = (int)(base + excl);
    cur[tid] = excl;
    __syncthreads();
    for (int i = tid; i < st; i += 256) {
        u32 e = est[i];
        u32 pos = atomicAdd(&cur[(e >> 16) & 255u], 1u);
        esrc[base + pos] = (u16)(e & 0xFFFFu);
    }
    for (int i = SMAX + tid; i < size; i += 256) {
        u32 e = ebuf[base + i];
        u32 pos = atomicAdd(&cur[(e >> 16) & 255u], 1u);
        esrc[base + pos] = (u16)(e & 0xFFFFu);
    }
}

// ---------------- layer-0 BN stats over x + fused x->bf16 conversion ----------------
__global__ __launch_bounds__(256) void stats0_k(const float* __restrict__ A,
                                                u16* __restrict__ xb,
                                                float* __restrict__ stats_mc,
                                                int total4, int K) {
    __shared__ float sh[2 * H_IN];
    int tid = threadIdx.x;
    int csz = 2 * K;
    sh[tid] = 0.f;
    sh[tid + 256] = 0.f;
    __syncthreads();
    int gid = blockIdx.x * 256 + tid;
    int stride = gridDim.x * 256;
    int c0 = (gid * 4) % K;
    float s0=0.f,s1=0.f,s2=0.f,s3=0.f, q0=0.f,q1=0.f,q2=0.f,q3=0.f;
    const float4* A4 = (const float4*)A;
    ushort4* X4 = (ushort4*)xb;
    for (int i = gid; i < total4; i += stride) {
        float4 v = A4[i];
        ushort4 xv;
        xv.x = f2b(v.x); xv.y = f2b(v.y); xv.z = f2b(v.z); xv.w = f2b(v.w);
        X4[i] = xv;
        s0 += v.x; q0 += v.x * v.x;
        s1 += v.y; q1 += v.y * v.y;
        s2 += v.z; q2 += v.z * v.z;
        s3 += v.w; q3 += v.w * v.w;
    }
    atomicAdd(&sh[c0],     s0); atomicAdd(&sh[K + c0],     q0);
    atomicAdd(&sh[c0 + 1], s1); atomicAdd(&sh[K + c0 + 1], q1);
    atomicAdd(&sh[c0 + 2], s2); atomicAdd(&sh[K + c0 + 2], q2);
    atomicAdd(&sh[c0 + 3], s3); atomicAdd(&sh[K + c0 + 3], q3);
    __syncthreads();
    float* dst = stats_mc + (size_t)(blockIdx.x & (NCOPY - 1)) * csz;
    for (int i = tid; i < csz; i += 256) atomicAdd(&dst[i], sh[i]);
}

// fold: s/t from multi-copy stats, W'(bf16)=s*W, b' = bias + t@W
__global__ void fold_k(const float* __restrict__ W, const float* __restrict__ stats_mc,
                       const float* __restrict__ g, const float* __restrict__ b,
                       const float* __restrict__ bias, u16* __restrict__ Wpb,
                       float* __restrict__ bp, int N, int K) {
    int j = blockIdx.x;
    int k = threadIdx.x;
    int csz = 2 * K;
    float sum = 0.f, sumsq = 0.f;
#pragma unroll
    for (int c = 0; c < NCOPY; ++c) {
        sum   += stats_mc[(size_t)c * csz + k];
        sumsq += stats_mc[(size_t)c * csz + K + k];
    }
    float mu = sum / (float)N;
    float var = sumsq / (float)N - mu * mu;
    float s = g[k] * rsqrtf(var + BN_EPS);
    float t = b[k] - mu * s;
    float w = W[(size_t)k * H + j];
    Wpb[(size_t)k * H + j] = f2b(s * w);
    __shared__ float red[256];
    red[k] = t * w;
    __syncthreads();
    for (int o = blockDim.x >> 1; o > 0; o >>= 1) {
        if (k < o) red[k] += red[k + o];
        __syncthreads();
    }
    if (k == 0) bp[j] = bias[j] + red[0];
}

// ---------------- MFMA GEMM: Yb = Ab(bf16) * Wpb(bf16), bf16 out ----------------
template<int KT>   // KT = K/32
__global__ __launch_bounds__(256) void gemm_mfma_k(const u16* __restrict__ Ab,
                                                   const u16* __restrict__ Bb,
                                                   u16* __restrict__ Yb, int M) {
    const int K = KT * 32;
    int tid = threadIdx.x;
    int w = tid >> 6;
    int lane = tid & 63;
    int m16 = lane & 15;
    int q = lane >> 4;

    bf16x8 bfrag[KT][2];
#pragma unroll
    for (int t = 0; t < KT; ++t)
#pragma unroll
        for (int p = 0; p < 2; ++p) {
            int ncol = 32 * w + 16 * p + m16;
#pragma unroll
            for (int j = 0; j < 8; ++j)
                bfrag[t][p][j] = (short)Bb[(size_t)(32 * t + 8 * q + j) * H + ncol];
        }

    int nchunk = M >> 4;
    for (int c = blockIdx.x; c < nchunk; c += gridDim.x) {
        int m0 = c << 4;
        const u16* Arow = Ab + (size_t)(m0 + m16) * K + 8 * q;
        bf16x8 afrag[KT];
#pragma unroll
        for (int t = 0; t < KT; ++t)
            afrag[t] = *(const bf16x8*)(Arow + 32 * t);
        f32x4 acc0 = {0.f, 0.f, 0.f, 0.f}, acc1 = {0.f, 0.f, 0.f, 0.f};
#pragma unroll
        for (int t = 0; t < KT; ++t) {
            acc0 = __builtin_amdgcn_mfma_f32_16x16x32_bf16(afrag[t], bfrag[t][0], acc0, 0, 0, 0);
            acc1 = __builtin_amdgcn_mfma_f32_16x16x32_bf16(afrag[t], bfrag[t][1], acc1, 0, 0, 0);
        }
        u16* Crow = Yb + (size_t)(m0 + q * 4) * H + 32 * w + m16;
#pragma unroll
        for (int i = 0; i < 4; ++i) {
            Crow[(size_t)i * H]      = f2b(acc0[i]);
            Crow[(size_t)i * H + 16] = f2b(acc1[i]);
        }
    }
}

// ---------------- CSR aggregation (bf16 gather, u16 esrc, on-the-fly norm) ----------------
// O[i] = bp + dinv[i]*(dinv[i]*Y[i] + sum_p dinv[src]*Y[src])
__global__ __launch_bounds__(256) void csragg_k(const int* __restrict__ rowptr,
                                                const u16* __restrict__ esrc,
                                                const u16* __restrict__ Yb,
                                                const float* __restrict__ dinv,
                                                const float* __restrict__ bp,
                                                u16* __restrict__ Ob,
                                                float* __restrict__ Of,
                                                float* __restrict__ stats_mc,
                                                int do_stats, int N) {
    __shared__ float sh[1024];                // 4 waves x 256 bins
    int tid = threadIdx.x;
    int node = blockIdx.x * 16 + (tid >> 4);
    int fl = tid & 15;
    float o[8] = {0.f,0.f,0.f,0.f,0.f,0.f,0.f,0.f};
    if (node < N) {
        const us8* Y8 = (const us8*)Yb;
        float dn = dinv[node];
        float acc[8];
        {
            us8 ys = Y8[(size_t)node * 16 + fl];
#pragma unroll
            for (int j = 0; j < 8; ++j) acc[j] = dn * b2f(ys[j]);
        }
        int s = rowptr[node], e = rowptr[node + 1];
        int p = s;
        for (; p + 1 < e; p += 2) {
            int s0 = esrc[p], s1 = esrc[p + 1];
            float n0 = dinv[s0], n1 = dinv[s1];
            us8 v0 = Y8[(size_t)s0 * 16 + fl];
            us8 v1 = Y8[(size_t)s1 * 16 + fl];
#pragma unroll
            for (int j = 0; j < 8; ++j) acc[j] += n0 * b2f(v0[j]);
#pragma unroll
            for (int j = 0; j < 8; ++j) acc[j] += n1 * b2f(v1[j]);
        }
        if (p < e) {
            int s0 = esrc[p];
            float n0 = dinv[s0];
            us8 v0 = Y8[(size_t)s0 * 16 + fl];
#pragma unroll
            for (int j = 0; j < 8; ++j) acc[j] += n0 * b2f(v0[j]);
        }
        float4 b0 = ((const float4*)bp)[fl * 2];
        float4 b1 = ((const float4*)bp)[fl * 2 + 1];
        o[0] = b0.x + dn * acc[0]; o[1] = b0.y + dn * acc[1];
        o[2] = b0.z + dn * acc[2]; o[3] = b0.w + dn * acc[3];
        o[4] = b1.x + dn * acc[4]; o[5] = b1.y + dn * acc[5];
        o[6] = b1.z + dn * acc[6]; o[7] = b1.w + dn * acc[7];
        if (Of) {
            float4* O4 = (float4*)Of;
            O4[(size_t)node * 32 + fl * 2]     = make_float4(o[0], o[1], o[2], o[3]);
            O4[(size_t)node * 32 + fl * 2 + 1] = make_float4(o[4], o[5], o[6], o[7]);
        } else {
            us8 ov;
#pragma unroll
            for (int j = 0; j < 8; ++j) ov[j] = f2b(o[j]);
            *(us8*)(Ob + (size_t)node * H + fl * 8) = ov;
        }
    }
    if (do_stats) {
        float sv[16];
#pragma unroll
        for (int j = 0; j < 8; ++j) { sv[j] = o[j]; sv[8 + j] = o[j] * o[j]; }
#pragma unroll
        for (int j = 0; j < 16; ++j) {
            sv[j] += __shfl_xor(sv[j], 16, 64);
            sv[j] += __shfl_xor(sv[j], 32, 64);
        }
        int lane = tid & 63, wv = tid >> 6;
        if (lane < 16) {
            float* base = sh + wv * 256;
#pragma unroll
            for (int j = 0; j < 8; ++j) {
                base[fl * 8 + j]       = sv[j];
                base[128 + fl * 8 + j] = sv[8 + j];
            }
        }
        __syncthreads();
        float v = sh[tid] + sh[256 + tid] + sh[512 + tid] + sh[768 + tid];
        atomicAdd(&stats_mc[(size_t)(blockIdx.x & (NCOPY - 1)) * (2 * H) + tid], v);
    }
}

// ---------------- host ----------------
extern "C" void kernel_launch(void* const* d_in, const int* in_sizes, int n_in,
                              void* d_out, int out_size, void* d_ws, size_t ws_size,
                              hipStream_t stream) {
    const float* x     = (const float*)d_in[0];
    const int*   ei    = (const int*)d_in[1];
    const float* bnfg  = (const float*)d_in[2];
    const float* bnfb  = (const float*)d_in[3];
    const float* Wfeat = (const float*)d_in[4];
    const float* bfeat = (const float*)d_in[5];
    const float* bng   = (const float*)d_in[6];
    const float* bnb   = (const float*)d_in[7];
    const float* Ws    = (const float*)d_in[8];
    const float* bs    = (const float*)d_in[9];

    int N = in_sizes[0] / H_IN;      // 50000  (must be < 65536 for u16 esrc)
    int E = in_sizes[1] / 2;         // 800000
    const int* row = ei;
    const int* col = ei + E;

    int halfN  = (N + 1) / 2;        // 25000
    int hwords = (halfN + 1) / 2;    // 12500
    int NB     = (N + 255) >> 8;     // 196 buckets

    char* p = (char*)d_ws;
    auto alloc = [&](size_t bytes) { char* r = p; p += (bytes + 63) & ~size_t(63); return r; };
    float* dinv      = (float*)alloc(N * 4);
    float* stats_mc  = (float*)alloc(NCOPY * 2 * H_IN * 4);
    u16*   Wpb       = (u16*)alloc(H_IN * H * 2);
    float* bp        = (float*)alloc(H * 4);
    u32*   hist_part = (u32*)alloc((size_t)NSLICE * 2 * hwords * 4);
    u32*   bcnt_part = (u32*)alloc(NSLICE * 256 * 4);
    u32*   boff      = (u32*)alloc(NSLICE * 256 * 4);
    u32*   bbase     = (u32*)alloc(260 * 4);
    int*   rowptr    = (int*)alloc((N + 1) * 4);
    u32*   ebuf      = (u32*)alloc((size_t)E * 4);
    u16*   esrc      = (u16*)alloc((size_t)E * 2);
    u16*   xb        = (u16*)alloc((size_t)N * H_IN * 2);
    u16*   Yb        = (u16*)alloc((size_t)N * H * 2);
    u16*   ACTb      = (u16*)alloc((size_t)N * H * 2);

    float* out = (float*)d_out;

    // graph prologue: LDS-histogram radix CSR build (no random global atomics)
    size_t r1_lds = (size_t)(hwords + 256) * 4;
    radix1_k<<<2 * NSLICE, 256, r1_lds, stream>>>(row, col, hist_part, bcnt_part, E, halfN, hwords);
    scanb_k<<<1, 256, 0, stream>>>(bcnt_part, boff, bbase);
    dinv2_k<<<(2 * hwords + 255) / 256, 256, 0, stream>>>(hist_part, dinv, N, halfN, hwords);
    scat2_k<<<NSLICE, 256, 0, stream>>>(row, col, boff, ebuf, E);
    sortb_k<<<NB, 256, 0, stream>>>(ebuf, bbase, rowptr, esrc, N);

    // layer-0 BN stats over x (K=256) + x -> bf16
    hipMemsetAsync(stats_mc, 0, NCOPY * 2 * H_IN * sizeof(float), stream);
    stats0_k<<<512, 256, 0, stream>>>(x, xb, stats_mc, N * H_IN / 4, H_IN);

    // 4 layers; layer 0 reads xb (K=256), layers 1..3 read ACTb (K=128)
    for (int l = 0; l < 4; ++l) {
        const u16* Ab     = (l == 0) ? xb : ACTb;
        int K             = (l == 0) ? H_IN : H;
        const float* W    = (l == 0) ? Wfeat : Ws + (size_t)(l - 1) * H * H;
        const float* bias = (l == 0) ? bfeat : bs + (size_t)(l - 1) * H;
        const float* g    = (l == 0) ? bnfg : bng + (size_t)(l - 1) * H;
        const float* bb   = (l == 0) ? bnfb : bnb + (size_t)(l - 1) * H;
        int do_stats      = (l < 3);

        fold_k<<<H, K, 0, stream>>>(W, stats_mc, g, bb, bias, Wpb, bp, N, K);
        if (l == 0) gemm_mfma_k<8><<<512, 256, 0, stream>>>(Ab, Wpb, Yb, N);
        else        gemm_mfma_k<4><<<512, 256, 0, stream>>>(Ab, Wpb, Yb, N);
        if (do_stats)
            hipMemsetAsync(stats_mc, 0, NCOPY * 2 * H * sizeof(float), stream);
        csragg_k<<<(N + 15) / 16, 256, 0, stream>>>(rowptr, esrc, Yb, dinv, bp,
                                                    ACTb, (l == 3) ? out : nullptr,
                                                    stats_mc, do_stats, N);
    }
}

// Round 9
// 397.275 us; speedup vs baseline: 1.0794x; 1.0794x over previous
//
#include <hip/hip_runtime.h>
#include <hip/hip_bf16.h>

#define H_IN 256
#define H    128
#define BN_EPS 1e-5f
#define NCOPY 32
#define NSLICE 256   // edge slices for radix pipeline
#define SMAX 5120    // sortb LDS staging capacity (max bucket ~4400)

using u16 = unsigned short;
using u32 = unsigned int;
typedef __attribute__((ext_vector_type(8))) unsigned short us8;
typedef __attribute__((ext_vector_type(8))) short bf16x8;
typedef __attribute__((ext_vector_type(4))) float f32x4;

__device__ __forceinline__ float b2f(u16 u) {
    return __uint_as_float(((u32)u) << 16);
}
__device__ __forceinline__ u16 f2b(float f) {  // round-to-nearest-even
    u32 u = __float_as_uint(f);
    u += 0x7FFF + ((u >> 16) & 1);
    return (u16)(u >> 16);
}

// ---------------- radix pass 1: LDS row-histogram halves + coarse col-bucket counts ----------------
// grid = 2*NSLICE blocks; block b: slice = b>>1, half = b&1.
__global__ __launch_bounds__(256) void radix1_k(const int* __restrict__ row,
                                                const int* __restrict__ col,
                                                u32* __restrict__ hist_part,
                                                u32* __restrict__ bcnt_part,
                                                int E, int halfN, int hwords) {
    extern __shared__ u32 lds[];
    u32* hist = lds;
    u32* bcnt = lds + hwords;
    int tid = threadIdx.x;
    int slice = blockIdx.x >> 1;
    int half = blockIdx.x & 1;
    for (int i = tid; i < hwords; i += 256) hist[i] = 0;
    bcnt[tid] = 0;
    __syncthreads();

    int len = (E + NSLICE - 1) / NSLICE;
    int e0 = slice * len;
    int e1 = min(e0 + len, E);
    int lo = half * halfN;
    for (int e = e0 + tid; e < e1; e += 256) {
        int r = row[e] - lo;
        if ((u32)r < (u32)halfN)
            atomicAdd(&hist[r >> 1], 1u << ((r & 1) << 4));
        if (half == 0) atomicAdd(&bcnt[((u32)col[e]) >> 8], 1u);
    }
    __syncthreads();
    u32* hdst = hist_part + (size_t)blockIdx.x * hwords;
    for (int i = tid; i < hwords; i += 256) hdst[i] = hist[i];
    if (half == 0) bcnt_part[slice * 256 + tid] = bcnt[tid];
}

// ---------------- parallel scan of bucket counts ----------------
// a: block k = bucket; threads = slices. Per-slice exclusive offsets + bucket total.
__global__ __launch_bounds__(256) void scanb_a_k(const u32* __restrict__ bcnt_part,
                                                 u32* __restrict__ boff,
                                                 u32* __restrict__ btot) {
    __shared__ u32 sh[256];
    int k = blockIdx.x;
    int t = threadIdx.x;
    u32 v = bcnt_part[t * 256 + k];
    sh[t] = v;
    __syncthreads();
    for (int o = 1; o < 256; o <<= 1) {
        u32 x = (t >= o) ? sh[t - o] : 0;
        __syncthreads();
        sh[t] += x;
        __syncthreads();
    }
    boff[t * 256 + k] = sh[t] - v;        // exclusive within bucket
    if (t == 255) btot[k] = sh[255];
}

// b: single small scan of bucket totals -> bbase
__global__ void scanb_b_k(const u32* __restrict__ btot, u32* __restrict__ bbase) {
    __shared__ u32 sh[256];
    int k = threadIdx.x;
    u32 v = btot[k];
    sh[k] = v;
    __syncthreads();
    for (int o = 1; o < 256; o <<= 1) {
        u32 x = (k >= o) ? sh[k - o] : 0;
        __syncthreads();
        sh[k] += x;
        __syncthreads();
    }
    bbase[k] = sh[k] - v;
    if (k == 255) bbase[256] = sh[255];   // == E
}

// ---------------- reduce histogram partials -> dinv ----------------
__global__ void dinv2_k(const u32* __restrict__ hist_part, float* __restrict__ dinv,
                        int N, int halfN, int hwords) {
    int w = blockIdx.x * blockDim.x + threadIdx.x;   // word in [0, 2*hwords)
    if (w >= 2 * hwords) return;
    int h = (w >= hwords) ? 1 : 0;
    int lw = w - h * hwords;
    u32 v = 0;
    for (int s = 0; s < NSLICE; ++s) v += hist_part[(size_t)(s * 2 + h) * hwords + lw];
    int n = h * halfN + 2 * lw;
    if (n < N)     dinv[n]     = rsqrtf((float)(v & 0xFFFF) + 1.0f);
    if (n + 1 < N) dinv[n + 1] = rsqrtf((float)(v >> 16) + 1.0f);
}

// ---------------- scatter edges into coarse buckets (LDS cursors) ----------------
// grid = NSLICE blocks. Edge record: row (16b low) | col&255 (bits 16..23)
__global__ __launch_bounds__(256) void scat2_k(const int* __restrict__ row,
                                               const int* __restrict__ col,
                                               const u32* __restrict__ boff,
                                               const u32* __restrict__ bbase,
                                               u32* __restrict__ ebuf, int E) {
    __shared__ u32 cur[256];
    int tid = threadIdx.x;
    int slice = blockIdx.x;
    cur[tid] = boff[slice * 256 + tid] + bbase[tid];
    __syncthreads();
    int len = (E + NSLICE - 1) / NSLICE;
    int e0 = slice * len;
    int e1 = min(e0 + len, E);
    for (int e = e0 + tid; e < e1; e += 256) {
        u32 r = (u32)row[e];
        u32 c = (u32)col[e];
        u32 pos = atomicAdd(&cur[c >> 8], 1u);
        ebuf[pos] = r | ((c & 255u) << 16);
    }
}

// ---------------- per-bucket LDS counting sort -> exact CSR (esrc as u16) ----------------
__global__ __launch_bounds__(256) void sortb_k(const u32* __restrict__ ebuf,
                                               const u32* __restrict__ bbase,
                                               int* __restrict__ rowptr,
                                               u16* __restrict__ esrc, int N) {
    __shared__ u32 est[SMAX];
    __shared__ u32 hist[256], scanv[256], cur[256];
    int b = blockIdx.x, tid = threadIdx.x;
    u32 base = bbase[b];
    int size = (int)(bbase[b + 1] - base);
    int st = min(size, SMAX);
    hist[tid] = 0;
    __syncthreads();
    for (int i = tid; i < st; i += 256) {
        u32 e = ebuf[base + i];
        est[i] = e;
        atomicAdd(&hist[(e >> 16) & 255u], 1u);
    }
    for (int i = SMAX + tid; i < size; i += 256) {
        u32 e = ebuf[base + i];
        atomicAdd(&hist[(e >> 16) & 255u], 1u);
    }
    __syncthreads();
    u32 own = hist[tid];
    scanv[tid] = own;
    __syncthreads();
    for (int o = 1; o < 256; o <<= 1) {
        u32 t = (tid >= o) ? scanv[tid - o] : 0;
        __syncthreads();
        scanv[tid] += t;
        __syncthreads();
    }
    u32 excl = scanv[tid] - own;
    int idx = (b << 8) + tid;
    if (idx <= N) rowptr[idx] = (int)(base + excl);
    cur[tid] = excl;
    __syncthreads();
    for (int i = tid; i < st; i += 256) {
        u32 e = est[i];
        u32 pos = atomicAdd(&cur[(e >> 16) & 255u], 1u);
        esrc[base + pos] = (u16)(e & 0xFFFFu);
    }
    for (int i = SMAX + tid; i < size; i += 256) {
        u32 e = ebuf[base + i];
        u32 pos = atomicAdd(&cur[(e >> 16) & 255u], 1u);
        esrc[base + pos] = (u16)(e & 0xFFFFu);
    }
}

// ---------------- layer-0 BN stats over x + fused x->bf16 conversion ----------------
__global__ __launch_bounds__(256) void stats0_k(const float* __restrict__ A,
                                                u16* __restrict__ xb,
                                                float* __restrict__ stats_mc,
                                                int total4, int K) {
    __shared__ float sh[2 * H_IN];
    int tid = threadIdx.x;
    int csz = 2 * K;
    sh[tid] = 0.f;
    sh[tid + 256] = 0.f;
    __syncthreads();
    int gid = blockIdx.x * 256 + tid;
    int stride = gridDim.x * 256;
    int c0 = (gid * 4) % K;
    float s0=0.f,s1=0.f,s2=0.f,s3=0.f, q0=0.f,q1=0.f,q2=0.f,q3=0.f;
    const float4* A4 = (const float4*)A;
    ushort4* X4 = (ushort4*)xb;
    for (int i = gid; i < total4; i += stride) {
        float4 v = A4[i];
        ushort4 xv;
        xv.x = f2b(v.x); xv.y = f2b(v.y); xv.z = f2b(v.z); xv.w = f2b(v.w);
        X4[i] = xv;
        s0 += v.x; q0 += v.x * v.x;
        s1 += v.y; q1 += v.y * v.y;
        s2 += v.z; q2 += v.z * v.z;
        s3 += v.w; q3 += v.w * v.w;
    }
    atomicAdd(&sh[c0],     s0); atomicAdd(&sh[K + c0],     q0);
    atomicAdd(&sh[c0 + 1], s1); atomicAdd(&sh[K + c0 + 1], q1);
    atomicAdd(&sh[c0 + 2], s2); atomicAdd(&sh[K + c0 + 2], q2);
    atomicAdd(&sh[c0 + 3], s3); atomicAdd(&sh[K + c0 + 3], q3);
    __syncthreads();
    float* dst = stats_mc + (size_t)(blockIdx.x & (NCOPY - 1)) * csz;
    for (int i = tid; i < csz; i += 256) atomicAdd(&dst[i], sh[i]);
}

// fold: s/t from multi-copy stats, W'(bf16)=s*W, b' = bias + t@W
__global__ void fold_k(const float* __restrict__ W, const float* __restrict__ stats_mc,
                       const float* __restrict__ g, const float* __restrict__ b,
                       const float* __restrict__ bias, u16* __restrict__ Wpb,
                       float* __restrict__ bp, int N, int K) {
    int j = blockIdx.x;
    int k = threadIdx.x;
    int csz = 2 * K;
    float sum = 0.f, sumsq = 0.f;
#pragma unroll
    for (int c = 0; c < NCOPY; ++c) {
        sum   += stats_mc[(size_t)c * csz + k];
        sumsq += stats_mc[(size_t)c * csz + K + k];
    }
    float mu = sum / (float)N;
    float var = sumsq / (float)N - mu * mu;
    float s = g[k] * rsqrtf(var + BN_EPS);
    float t = b[k] - mu * s;
    float w = W[(size_t)k * H + j];
    Wpb[(size_t)k * H + j] = f2b(s * w);
    __shared__ float red[256];
    red[k] = t * w;
    __syncthreads();
    for (int o = blockDim.x >> 1; o > 0; o >>= 1) {
        if (k < o) red[k] += red[k + o];
        __syncthreads();
    }
    if (k == 0) bp[j] = bias[j] + red[0];
}

// ---------------- MFMA GEMM: Yb = Ab(bf16) * Wpb(bf16), bf16 out ----------------
template<int KT>   // KT = K/32
__global__ __launch_bounds__(256) void gemm_mfma_k(const u16* __restrict__ Ab,
                                                   const u16* __restrict__ Bb,
                                                   u16* __restrict__ Yb, int M) {
    const int K = KT * 32;
    int tid = threadIdx.x;
    int w = tid >> 6;
    int lane = tid & 63;
    int m16 = lane & 15;
    int q = lane >> 4;

    bf16x8 bfrag[KT][2];
#pragma unroll
    for (int t = 0; t < KT; ++t)
#pragma unroll
        for (int p = 0; p < 2; ++p) {
            int ncol = 32 * w + 16 * p + m16;
#pragma unroll
            for (int j = 0; j < 8; ++j)
                bfrag[t][p][j] = (short)Bb[(size_t)(32 * t + 8 * q + j) * H + ncol];
        }

    int nchunk = M >> 4;
    for (int c = blockIdx.x; c < nchunk; c += gridDim.x) {
        int m0 = c << 4;
        const u16* Arow = Ab + (size_t)(m0 + m16) * K + 8 * q;
        bf16x8 afrag[KT];
#pragma unroll
        for (int t = 0; t < KT; ++t)
            afrag[t] = *(const bf16x8*)(Arow + 32 * t);
        f32x4 acc0 = {0.f, 0.f, 0.f, 0.f}, acc1 = {0.f, 0.f, 0.f, 0.f};
#pragma unroll
        for (int t = 0; t < KT; ++t) {
            acc0 = __builtin_amdgcn_mfma_f32_16x16x32_bf16(afrag[t], bfrag[t][0], acc0, 0, 0, 0);
            acc1 = __builtin_amdgcn_mfma_f32_16x16x32_bf16(afrag[t], bfrag[t][1], acc1, 0, 0, 0);
        }
        u16* Crow = Yb + (size_t)(m0 + q * 4) * H + 32 * w + m16;
#pragma unroll
        for (int i = 0; i < 4; ++i) {
            Crow[(size_t)i * H]      = f2b(acc0[i]);
            Crow[(size_t)i * H + 16] = f2b(acc1[i]);
        }
    }
}

// ---------------- CSR aggregation (bf16 gather, u16 esrc, on-the-fly norm) ----------------
__global__ __launch_bounds__(256) void csragg_k(const int* __restrict__ rowptr,
                                                const u16* __restrict__ esrc,
                                                const u16* __restrict__ Yb,
                                                const float* __restrict__ dinv,
                                                const float* __restrict__ bp,
                                                u16* __restrict__ Ob,
                                                float* __restrict__ Of,
                                                float* __restrict__ stats_mc,
                                                int do_stats, int N) {
    __shared__ float sh[1024];                // 4 waves x 256 bins
    int tid = threadIdx.x;
    int node = blockIdx.x * 16 + (tid >> 4);
    int fl = tid & 15;
    float o[8] = {0.f,0.f,0.f,0.f,0.f,0.f,0.f,0.f};
    if (node < N) {
        const us8* Y8 = (const us8*)Yb;
        float dn = dinv[node];
        float acc[8];
        {
            us8 ys = Y8[(size_t)node * 16 + fl];
#pragma unroll
            for (int j = 0; j < 8; ++j) acc[j] = dn * b2f(ys[j]);
        }
        int s = rowptr[node], e = rowptr[node + 1];
        int p = s;
        for (; p + 1 < e; p += 2) {
            int s0 = esrc[p], s1 = esrc[p + 1];
            float n0 = dinv[s0], n1 = dinv[s1];
            us8 v0 = Y8[(size_t)s0 * 16 + fl];
            us8 v1 = Y8[(size_t)s1 * 16 + fl];
#pragma unroll
            for (int j = 0; j < 8; ++j) acc[j] += n0 * b2f(v0[j]);
#pragma unroll
            for (int j = 0; j < 8; ++j) acc[j] += n1 * b2f(v1[j]);
        }
        if (p < e) {
            int s0 = esrc[p];
            float n0 = dinv[s0];
            us8 v0 = Y8[(size_t)s0 * 16 + fl];
#pragma unroll
            for (int j = 0; j < 8; ++j) acc[j] += n0 * b2f(v0[j]);
        }
        float4 b0 = ((const float4*)bp)[fl * 2];
        float4 b1 = ((const float4*)bp)[fl * 2 + 1];
        o[0] = b0.x + dn * acc[0]; o[1] = b0.y + dn * acc[1];
        o[2] = b0.z + dn * acc[2]; o[3] = b0.w + dn * acc[3];
        o[4] = b1.x + dn * acc[4]; o[5] = b1.y + dn * acc[5];
        o[6] = b1.z + dn * acc[6]; o[7] = b1.w + dn * acc[7];
        if (Of) {
            float4* O4 = (float4*)Of;
            O4[(size_t)node * 32 + fl * 2]     = make_float4(o[0], o[1], o[2], o[3]);
            O4[(size_t)node * 32 + fl * 2 + 1] = make_float4(o[4], o[5], o[6], o[7]);
        } else {
            us8 ov;
#pragma unroll
            for (int j = 0; j < 8; ++j) ov[j] = f2b(o[j]);
            *(us8*)(Ob + (size_t)node * H + fl * 8) = ov;
        }
    }
    if (do_stats) {
        float sv[16];
#pragma unroll
        for (int j = 0; j < 8; ++j) { sv[j] = o[j]; sv[8 + j] = o[j] * o[j]; }
#pragma unroll
        for (int j = 0; j < 16; ++j) {
            sv[j] += __shfl_xor(sv[j], 16, 64);
            sv[j] += __shfl_xor(sv[j], 32, 64);
        }
        int lane = tid & 63, wv = tid >> 6;
        if (lane < 16) {
            float* base = sh + wv * 256;
#pragma unroll
            for (int j = 0; j < 8; ++j) {
                base[fl * 8 + j]       = sv[j];
                base[128 + fl * 8 + j] = sv[8 + j];
            }
        }
        __syncthreads();
        float v = sh[tid] + sh[256 + tid] + sh[512 + tid] + sh[768 + tid];
        atomicAdd(&stats_mc[(size_t)(blockIdx.x & (NCOPY - 1)) * (2 * H) + tid], v);
    }
}

// ---------------- host ----------------
extern "C" void kernel_launch(void* const* d_in, const int* in_sizes, int n_in,
                              void* d_out, int out_size, void* d_ws, size_t ws_size,
                              hipStream_t stream) {
    const float* x     = (const float*)d_in[0];
    const int*   ei    = (const int*)d_in[1];
    const float* bnfg  = (const float*)d_in[2];
    const float* bnfb  = (const float*)d_in[3];
    const float* Wfeat = (const float*)d_in[4];
    const float* bfeat = (const float*)d_in[5];
    const float* bng   = (const float*)d_in[6];
    const float* bnb   = (const float*)d_in[7];
    const float* Ws    = (const float*)d_in[8];
    const float* bs    = (const float*)d_in[9];

    int N = in_sizes[0] / H_IN;      // 50000  (must be < 65536 for u16 esrc)
    int E = in_sizes[1] / 2;         // 800000
    const int* row = ei;
    const int* col = ei + E;

    int halfN  = (N + 1) / 2;        // 25000
    int hwords = (halfN + 1) / 2;    // 12500
    int NB     = (N + 255) >> 8;     // 196 buckets

    char* p = (char*)d_ws;
    auto alloc = [&](size_t bytes) { char* r = p; p += (bytes + 63) & ~size_t(63); return r; };
    float* dinv      = (float*)alloc(N * 4);
    float* stats_mc  = (float*)alloc(NCOPY * 2 * H_IN * 4);
    u16*   Wpb       = (u16*)alloc(H_IN * H * 2);
    float* bp        = (float*)alloc(H * 4);
    u32*   hist_part = (u32*)alloc((size_t)NSLICE * 2 * hwords * 4);
    u32*   bcnt_part = (u32*)alloc(NSLICE * 256 * 4);
    u32*   boff      = (u32*)alloc(NSLICE * 256 * 4);
    u32*   btot      = (u32*)alloc(256 * 4);
    u32*   bbase     = (u32*)alloc(260 * 4);
    int*   rowptr    = (int*)alloc((N + 1) * 4);
    u32*   ebuf      = (u32*)alloc((size_t)E * 4);
    u16*   esrc      = (u16*)alloc((size_t)E * 2);
    u16*   xb        = (u16*)alloc((size_t)N * H_IN * 2);
    u16*   Yb        = (u16*)alloc((size_t)N * H * 2);
    u16*   ACTb      = (u16*)alloc((size_t)N * H * 2);

    float* out = (float*)d_out;

    // graph prologue: LDS-histogram radix CSR build (no random global atomics)
    size_t r1_lds = (size_t)(hwords + 256) * 4;
    radix1_k<<<2 * NSLICE, 256, r1_lds, stream>>>(row, col, hist_part, bcnt_part, E, halfN, hwords);
    scanb_a_k<<<256, 256, 0, stream>>>(bcnt_part, boff, btot);
    scanb_b_k<<<1, 256, 0, stream>>>(btot, bbase);
    dinv2_k<<<(2 * hwords + 255) / 256, 256, 0, stream>>>(hist_part, dinv, N, halfN, hwords);
    scat2_k<<<NSLICE, 256, 0, stream>>>(row, col, boff, bbase, ebuf, E);
    sortb_k<<<NB, 256, 0, stream>>>(ebuf, bbase, rowptr, esrc, N);

    // layer-0 BN stats over x (K=256) + x -> bf16
    hipMemsetAsync(stats_mc, 0, NCOPY * 2 * H_IN * sizeof(float), stream);
    stats0_k<<<512, 256, 0, stream>>>(x, xb, stats_mc, N * H_IN / 4, H_IN);

    // 4 layers; layer 0 reads xb (K=256), layers 1..3 read ACTb (K=128)
    for (int l = 0; l < 4; ++l) {
        const u16* Ab     = (l == 0) ? xb : ACTb;
        int K             = (l == 0) ? H_IN : H;
        const float* W    = (l == 0) ? Wfeat : Ws + (size_t)(l - 1) * H * H;
        const float* bias = (l == 0) ? bfeat : bs + (size_t)(l - 1) * H;
        const float* g    = (l == 0) ? bnfg : bng + (size_t)(l - 1) * H;
        const float* bb   = (l == 0) ? bnfb : bnb + (size_t)(l - 1) * H;
        int do_stats      = (l < 3);

        fold_k<<<H, K, 0, stream>>>(W, stats_mc, g, bb, bias, Wpb, bp, N, K);
        if (l == 0) gemm_mfma_k<8><<<512, 256, 0, stream>>>(Ab, Wpb, Yb, N);
        else        gemm_mfma_k<4><<<512, 256, 0, stream>>>(Ab, Wpb, Yb, N);
        if (do_stats)
            hipMemsetAsync(stats_mc, 0, NCOPY * 2 * H * sizeof(float), stream);
        csragg_k<<<(N + 15) / 16, 256, 0, stream>>>(rowptr, esrc, Yb, dinv, bp,
                                                    ACTb, (l == 3) ? out : nullptr,
                                                    stats_mc, do_stats, N);
    }
}

// Round 10
// 378.783 us; speedup vs baseline: 1.1321x; 1.0488x over previous
//
#include <hip/hip_runtime.h>
#include <hip/hip_bf16.h>

#define H_IN 256
#define H    128
#define BN_EPS 1e-5f
#define NCOPY 32
#define NSLICE 256   // edge slices for radix pipeline
#define SMAX 5120    // sortb LDS staging capacity (max bucket ~4400)
#define STATS_FLOATS (NCOPY * 2 * H_IN)   // 16384

using u16 = unsigned short;
using u32 = unsigned int;
typedef __attribute__((ext_vector_type(8))) unsigned short us8;
typedef __attribute__((ext_vector_type(8))) short bf16x8;
typedef __attribute__((ext_vector_type(4))) float f32x4;

__device__ __forceinline__ float b2f(u16 u) {
    return __uint_as_float(((u32)u) << 16);
}
__device__ __forceinline__ u16 f2b(float f) {  // round-to-nearest-even
    u32 u = __float_as_uint(f);
    u += 0x7FFF + ((u >> 16) & 1);
    return (u16)(u >> 16);
}

// ---------------- radix pass 1: LDS row-histogram halves + coarse col-bucket counts ----------------
// grid = 2*NSLICE blocks; block b: slice = b>>1, half = b&1.
__global__ __launch_bounds__(256) void radix1_k(const int* __restrict__ row,
                                                const int* __restrict__ col,
                                                u32* __restrict__ hist_part,
                                                u32* __restrict__ bcnt_part,
                                                int E, int halfN, int hwords) {
    extern __shared__ u32 lds[];
    u32* hist = lds;
    u32* bcnt = lds + hwords;
    int tid = threadIdx.x;
    int slice = blockIdx.x >> 1;
    int half = blockIdx.x & 1;
    for (int i = tid; i < hwords; i += 256) hist[i] = 0;
    bcnt[tid] = 0;
    __syncthreads();

    int len = (E + NSLICE - 1) / NSLICE;
    int e0 = slice * len;
    int e1 = min(e0 + len, E);
    int lo = half * halfN;
    for (int e = e0 + tid; e < e1; e += 256) {
        int r = row[e] - lo;
        if ((u32)r < (u32)halfN)
            atomicAdd(&hist[r >> 1], 1u << ((r & 1) << 4));
        if (half == 0) atomicAdd(&bcnt[((u32)col[e]) >> 8], 1u);
    }
    __syncthreads();
    u32* hdst = hist_part + (size_t)blockIdx.x * hwords;
    for (int i = tid; i < hwords; i += 256) hdst[i] = hist[i];
    if (half == 0) bcnt_part[slice * 256 + tid] = bcnt[tid];
}

// ---------------- merged mid kernel: scanb_a (blocks 0..255) | zero stats (next 64)
//                  | dinv reduce (rest).  All depend only on radix1. ----------------
#define ZB 64
__global__ __launch_bounds__(256) void mid_k(const u32* __restrict__ bcnt_part,
                                             u32* __restrict__ boff,
                                             u32* __restrict__ btot,
                                             const u32* __restrict__ hist_part,
                                             float* __restrict__ dinv,
                                             float* __restrict__ stats_mc,
                                             int N, int halfN, int hwords) {
    int b = blockIdx.x;
    int tid = threadIdx.x;
    if (b < 256) {
        // scanb_a: block = bucket, threads = slices
        __shared__ u32 sh[256];
        u32 v = bcnt_part[tid * 256 + b];
        sh[tid] = v;
        __syncthreads();
        for (int o = 1; o < 256; o <<= 1) {
            u32 x = (tid >= o) ? sh[tid - o] : 0;
            __syncthreads();
            sh[tid] += x;
            __syncthreads();
        }
        boff[tid * 256 + b] = sh[tid] - v;
        if (tid == 255) btot[b] = sh[255];
    } else if (b < 256 + ZB) {
        int i = (b - 256) * 256 + tid;
        if (i < STATS_FLOATS) stats_mc[i] = 0.f;
    } else {
        int w = (b - 256 - ZB) * 256 + tid;     // word in [0, 2*hwords)
        if (w >= 2 * hwords) return;
        int h = (w >= hwords) ? 1 : 0;
        int lw = w - h * hwords;
        u32 v = 0;
        for (int s = 0; s < NSLICE; ++s) v += hist_part[(size_t)(s * 2 + h) * hwords + lw];
        int n = h * halfN + 2 * lw;
        if (n < N)     dinv[n]     = rsqrtf((float)(v & 0xFFFF) + 1.0f);
        if (n + 1 < N) dinv[n + 1] = rsqrtf((float)(v >> 16) + 1.0f);
    }
}

// single small scan of bucket totals -> bbase
__global__ void scanb_b_k(const u32* __restrict__ btot, u32* __restrict__ bbase) {
    __shared__ u32 sh[256];
    int k = threadIdx.x;
    u32 v = btot[k];
    sh[k] = v;
    __syncthreads();
    for (int o = 1; o < 256; o <<= 1) {
        u32 x = (k >= o) ? sh[k - o] : 0;
        __syncthreads();
        sh[k] += x;
        __syncthreads();
    }
    bbase[k] = sh[k] - v;
    if (k == 255) bbase[256] = sh[255];   // == E
}

// ---------------- scatter edges into coarse buckets (LDS cursors) ----------------
__global__ __launch_bounds__(256) void scat2_k(const int* __restrict__ row,
                                               const int* __restrict__ col,
                                               const u32* __restrict__ boff,
                                               const u32* __restrict__ bbase,
                                               u32* __restrict__ ebuf, int E) {
    __shared__ u32 cur[256];
    int tid = threadIdx.x;
    int slice = blockIdx.x;
    cur[tid] = boff[slice * 256 + tid] + bbase[tid];
    __syncthreads();
    int len = (E + NSLICE - 1) / NSLICE;
    int e0 = slice * len;
    int e1 = min(e0 + len, E);
    for (int e = e0 + tid; e < e1; e += 256) {
        u32 r = (u32)row[e];
        u32 c = (u32)col[e];
        u32 pos = atomicAdd(&cur[c >> 8], 1u);
        ebuf[pos] = r | ((c & 255u) << 16);
    }
}

// ---------------- per-bucket LDS counting sort -> exact CSR (esrc as u16) ----------------
__global__ __launch_bounds__(256) void sortb_k(const u32* __restrict__ ebuf,
                                               const u32* __restrict__ bbase,
                                               int* __restrict__ rowptr,
                                               u16* __restrict__ esrc, int N) {
    __shared__ u32 est[SMAX];
    __shared__ u32 hist[256], scanv[256], cur[256];
    int b = blockIdx.x, tid = threadIdx.x;
    u32 base = bbase[b];
    int size = (int)(bbase[b + 1] - base);
    int st = min(size, SMAX);
    hist[tid] = 0;
    __syncthreads();
    for (int i = tid; i < st; i += 256) {
        u32 e = ebuf[base + i];
        est[i] = e;
        atomicAdd(&hist[(e >> 16) & 255u], 1u);
    }
    for (int i = SMAX + tid; i < size; i += 256) {
        u32 e = ebuf[base + i];
        atomicAdd(&hist[(e >> 16) & 255u], 1u);
    }
    __syncthreads();
    u32 own = hist[tid];
    scanv[tid] = own;
    __syncthreads();
    for (int o = 1; o < 256; o <<= 1) {
        u32 t = (tid >= o) ? scanv[tid - o] : 0;
        __syncthreads();
        scanv[tid] += t;
        __syncthreads();
    }
    u32 excl = scanv[tid] - own;
    int idx = (b << 8) + tid;
    if (idx <= N) rowptr[idx] = (int)(base + excl);
    cur[tid] = excl;
    __syncthreads();
    for (int i = tid; i < st; i += 256) {
        u32 e = est[i];
        u32 pos = atomicAdd(&cur[(e >> 16) & 255u], 1u);
        esrc[base + pos] = (u16)(e & 0xFFFFu);
    }
    for (int i = SMAX + tid; i < size; i += 256) {
        u32 e = ebuf[base + i];
        u32 pos = atomicAdd(&cur[(e >> 16) & 255u], 1u);
        esrc[base + pos] = (u16)(e & 0xFFFFu);
    }
}

// ---------------- layer-0 BN stats over x + fused x->bf16 conversion ----------------
__global__ __launch_bounds__(256) void stats0_k(const float* __restrict__ A,
                                                u16* __restrict__ xb,
                                                float* __restrict__ stats_mc,
                                                int total4, int K) {
    __shared__ float sh[2 * H_IN];
    int tid = threadIdx.x;
    int csz = 2 * K;
    sh[tid] = 0.f;
    sh[tid + 256] = 0.f;
    __syncthreads();
    int gid = blockIdx.x * 256 + tid;
    int stride = gridDim.x * 256;
    int c0 = (gid * 4) % K;
    float s0=0.f,s1=0.f,s2=0.f,s3=0.f, q0=0.f,q1=0.f,q2=0.f,q3=0.f;
    const float4* A4 = (const float4*)A;
    ushort4* X4 = (ushort4*)xb;
    for (int i = gid; i < total4; i += stride) {
        float4 v = A4[i];
        ushort4 xv;
        xv.x = f2b(v.x); xv.y = f2b(v.y); xv.z = f2b(v.z); xv.w = f2b(v.w);
        X4[i] = xv;
        s0 += v.x; q0 += v.x * v.x;
        s1 += v.y; q1 += v.y * v.y;
        s2 += v.z; q2 += v.z * v.z;
        s3 += v.w; q3 += v.w * v.w;
    }
    atomicAdd(&sh[c0],     s0); atomicAdd(&sh[K + c0],     q0);
    atomicAdd(&sh[c0 + 1], s1); atomicAdd(&sh[K + c0 + 1], q1);
    atomicAdd(&sh[c0 + 2], s2); atomicAdd(&sh[K + c0 + 2], q2);
    atomicAdd(&sh[c0 + 3], s3); atomicAdd(&sh[K + c0 + 3], q3);
    __syncthreads();
    float* dst = stats_mc + (size_t)(blockIdx.x & (NCOPY - 1)) * csz;
    for (int i = tid; i < csz; i += 256) atomicAdd(&dst[i], sh[i]);
}

// fold: s/t from multi-copy stats, TRANSPOSED W' (bf16): Wt[j][k] = s[k]W[k][j];
// b'[j] = bias[j] + sum_k t[k]W[k][j]
__global__ void fold_k(const float* __restrict__ W, const float* __restrict__ stats_mc,
                       const float* __restrict__ g, const float* __restrict__ b,
                       const float* __restrict__ bias, u16* __restrict__ Wt,
                       float* __restrict__ bp, int N, int K) {
    int j = blockIdx.x;
    int k = threadIdx.x;
    int csz = 2 * K;
    float sum = 0.f, sumsq = 0.f;
#pragma unroll
    for (int c = 0; c < NCOPY; ++c) {
        sum   += stats_mc[(size_t)c * csz + k];
        sumsq += stats_mc[(size_t)c * csz + K + k];
    }
    float mu = sum / (float)N;
    float var = sumsq / (float)N - mu * mu;
    float s = g[k] * rsqrtf(var + BN_EPS);
    float t = b[k] - mu * s;
    float w = W[(size_t)k * H + j];
    Wt[(size_t)j * K + k] = f2b(s * w);    // transposed: row j contiguous in k
    __shared__ float red[256];
    red[k] = t * w;
    __syncthreads();
    for (int o = blockDim.x >> 1; o > 0; o >>= 1) {
        if (k < o) red[k] += red[k + o];
        __syncthreads();
    }
    if (k == 0) bp[j] = bias[j] + red[0];
}

// ---------------- MFMA GEMM: Yb = Ab(bf16) * Wt(bf16,[n][k]), bf16 out ----------------
// Block 0 also zeroes stats_mc (fold already consumed it; csragg accumulates next).
template<int KT>   // KT = K/32
__global__ __launch_bounds__(256) void gemm_mfma_k(const u16* __restrict__ Ab,
                                                   const u16* __restrict__ Wt,
                                                   u16* __restrict__ Yb, int M,
                                                   float* __restrict__ stats_z) {
    const int K = KT * 32;
    int tid = threadIdx.x;
    if (stats_z && blockIdx.x == 0) {
        for (int i = tid; i < STATS_FLOATS; i += 256) stats_z[i] = 0.f;
    }
    int w = tid >> 6;
    int lane = tid & 63;
    int m16 = lane & 15;
    int q = lane >> 4;

    bf16x8 bfrag[KT][2];
#pragma unroll
    for (int t = 0; t < KT; ++t)
#pragma unroll
        for (int p = 0; p < 2; ++p) {
            int ncol = 32 * w + 16 * p + m16;
            bfrag[t][p] = *(const bf16x8*)(Wt + (size_t)ncol * K + 32 * t + 8 * q);
        }

    int nchunk = M >> 4;
    for (int c = blockIdx.x; c < nchunk; c += gridDim.x) {
        int m0 = c << 4;
        const u16* Arow = Ab + (size_t)(m0 + m16) * K + 8 * q;
        bf16x8 afrag[KT];
#pragma unroll
        for (int t = 0; t < KT; ++t)
            afrag[t] = *(const bf16x8*)(Arow + 32 * t);
        f32x4 acc0 = {0.f, 0.f, 0.f, 0.f}, acc1 = {0.f, 0.f, 0.f, 0.f};
#pragma unroll
        for (int t = 0; t < KT; ++t) {
            acc0 = __builtin_amdgcn_mfma_f32_16x16x32_bf16(afrag[t], bfrag[t][0], acc0, 0, 0, 0);
            acc1 = __builtin_amdgcn_mfma_f32_16x16x32_bf16(afrag[t], bfrag[t][1], acc1, 0, 0, 0);
        }
        u16* Crow = Yb + (size_t)(m0 + q * 4) * H + 32 * w + m16;
#pragma unroll
        for (int i = 0; i < 4; ++i) {
            Crow[(size_t)i * H]      = f2b(acc0[i]);
            Crow[(size_t)i * H + 16] = f2b(acc1[i]);
        }
    }
}

// ---------------- CSR aggregation (bf16 gather, u16 esrc, on-the-fly norm) ----------------
__global__ __launch_bounds__(256) void csragg_k(const int* __restrict__ rowptr,
                                                const u16* __restrict__ esrc,
                                                const u16* __restrict__ Yb,
                                                const float* __restrict__ dinv,
                                                const float* __restrict__ bp,
                                                u16* __restrict__ Ob,
                                                float* __restrict__ Of,
                                                float* __restrict__ stats_mc,
                                                int do_stats, int N) {
    __shared__ float sh[1024];                // 4 waves x 256 bins
    int tid = threadIdx.x;
    int node = blockIdx.x * 16 + (tid >> 4);
    int fl = tid & 15;
    float o[8] = {0.f,0.f,0.f,0.f,0.f,0.f,0.f,0.f};
    if (node < N) {
        const us8* Y8 = (const us8*)Yb;
        float dn = dinv[node];
        float acc[8];
        {
            us8 ys = Y8[(size_t)node * 16 + fl];
#pragma unroll
            for (int j = 0; j < 8; ++j) acc[j] = dn * b2f(ys[j]);
        }
        int s = rowptr[node], e = rowptr[node + 1];
        int p = s;
        for (; p + 3 < e; p += 4) {
            int s0 = esrc[p], s1 = esrc[p + 1], s2 = esrc[p + 2], s3 = esrc[p + 3];
            float n0 = dinv[s0], n1 = dinv[s1], n2 = dinv[s2], n3 = dinv[s3];
            us8 v0 = Y8[(size_t)s0 * 16 + fl];
            us8 v1 = Y8[(size_t)s1 * 16 + fl];
            us8 v2 = Y8[(size_t)s2 * 16 + fl];
            us8 v3 = Y8[(size_t)s3 * 16 + fl];
#pragma unroll
            for (int j = 0; j < 8; ++j) acc[j] += n0 * b2f(v0[j]);
#pragma unroll
            for (int j = 0; j < 8; ++j) acc[j] += n1 * b2f(v1[j]);
#pragma unroll
            for (int j = 0; j < 8; ++j) acc[j] += n2 * b2f(v2[j]);
#pragma unroll
            for (int j = 0; j < 8; ++j) acc[j] += n3 * b2f(v3[j]);
        }
        for (; p < e; ++p) {
            int s0 = esrc[p];
            float n0 = dinv[s0];
            us8 v0 = Y8[(size_t)s0 * 16 + fl];
#pragma unroll
            for (int j = 0; j < 8; ++j) acc[j] += n0 * b2f(v0[j]);
        }
        float4 b0 = ((const float4*)bp)[fl * 2];
        float4 b1 = ((const float4*)bp)[fl * 2 + 1];
        o[0] = b0.x + dn * acc[0]; o[1] = b0.y + dn * acc[1];
        o[2] = b0.z + dn * acc[2]; o[3] = b0.w + dn * acc[3];
        o[4] = b1.x + dn * acc[4]; o[5] = b1.y + dn * acc[5];
        o[6] = b1.z + dn * acc[6]; o[7] = b1.w + dn * acc[7];
        if (Of) {
            float4* O4 = (float4*)Of;
            O4[(size_t)node * 32 + fl * 2]     = make_float4(o[0], o[1], o[2], o[3]);
            O4[(size_t)node * 32 + fl * 2 + 1] = make_float4(o[4], o[5], o[6], o[7]);
        } else {
            us8 ov;
#pragma unroll
            for (int j = 0; j < 8; ++j) ov[j] = f2b(o[j]);
            *(us8*)(Ob + (size_t)node * H + fl * 8) = ov;
        }
    }
    if (do_stats) {
        float sv[16];
#pragma unroll
        for (int j = 0; j < 8; ++j) { sv[j] = o[j]; sv[8 + j] = o[j] * o[j]; }
#pragma unroll
        for (int j = 0; j < 16; ++j) {
            sv[j] += __shfl_xor(sv[j], 16, 64);
            sv[j] += __shfl_xor(sv[j], 32, 64);
        }
        int lane = tid & 63, wv = tid >> 6;
        if (lane < 16) {
            float* base = sh + wv * 256;
#pragma unroll
            for (int j = 0; j < 8; ++j) {
                base[fl * 8 + j]       = sv[j];
                base[128 + fl * 8 + j] = sv[8 + j];
            }
        }
        __syncthreads();
        float v = sh[tid] + sh[256 + tid] + sh[512 + tid] + sh[768 + tid];
        atomicAdd(&stats_mc[(size_t)(blockIdx.x & (NCOPY - 1)) * (2 * H) + tid], v);
    }
}

// ---------------- host ----------------
extern "C" void kernel_launch(void* const* d_in, const int* in_sizes, int n_in,
                              void* d_out, int out_size, void* d_ws, size_t ws_size,
                              hipStream_t stream) {
    const float* x     = (const float*)d_in[0];
    const int*   ei    = (const int*)d_in[1];
    const float* bnfg  = (const float*)d_in[2];
    const float* bnfb  = (const float*)d_in[3];
    const float* Wfeat = (const float*)d_in[4];
    const float* bfeat = (const float*)d_in[5];
    const float* bng   = (const float*)d_in[6];
    const float* bnb   = (const float*)d_in[7];
    const float* Ws    = (const float*)d_in[8];
    const float* bs    = (const float*)d_in[9];

    int N = in_sizes[0] / H_IN;      // 50000  (must be < 65536 for u16 esrc)
    int E = in_sizes[1] / 2;         // 800000
    const int* row = ei;
    const int* col = ei + E;

    int halfN  = (N + 1) / 2;        // 25000
    int hwords = (halfN + 1) / 2;    // 12500
    int NB     = (N + 255) >> 8;     // 196 buckets

    char* p = (char*)d_ws;
    auto alloc = [&](size_t bytes) { char* r = p; p += (bytes + 63) & ~size_t(63); return r; };
    float* dinv      = (float*)alloc(N * 4);
    float* stats_mc  = (float*)alloc(STATS_FLOATS * 4);
    u16*   Wt        = (u16*)alloc(H_IN * H * 2);
    float* bp        = (float*)alloc(H * 4);
    u32*   hist_part = (u32*)alloc((size_t)NSLICE * 2 * hwords * 4);
    u32*   bcnt_part = (u32*)alloc(NSLICE * 256 * 4);
    u32*   boff      = (u32*)alloc(NSLICE * 256 * 4);
    u32*   btot      = (u32*)alloc(256 * 4);
    u32*   bbase     = (u32*)alloc(260 * 4);
    int*   rowptr    = (int*)alloc((N + 1) * 4);
    u32*   ebuf      = (u32*)alloc((size_t)E * 4);
    u16*   esrc      = (u16*)alloc((size_t)E * 2);
    u16*   xb        = (u16*)alloc((size_t)N * H_IN * 2);
    u16*   Yb        = (u16*)alloc((size_t)N * H * 2);
    u16*   ACTb      = (u16*)alloc((size_t)N * H * 2);

    float* out = (float*)d_out;

    // graph prologue: LDS-histogram radix CSR build (no random global atomics)
    size_t r1_lds = (size_t)(hwords + 256) * 4;
    radix1_k<<<2 * NSLICE, 256, r1_lds, stream>>>(row, col, hist_part, bcnt_part, E, halfN, hwords);
    int dblocks = (2 * hwords + 255) / 256;
    mid_k<<<256 + ZB + dblocks, 256, 0, stream>>>(bcnt_part, boff, btot, hist_part,
                                                  dinv, stats_mc, N, halfN, hwords);
    scanb_b_k<<<1, 256, 0, stream>>>(btot, bbase);
    scat2_k<<<NSLICE, 256, 0, stream>>>(row, col, boff, bbase, ebuf, E);
    sortb_k<<<NB, 256, 0, stream>>>(ebuf, bbase, rowptr, esrc, N);

    // layer-0 BN stats over x (K=256) + x -> bf16
    stats0_k<<<512, 256, 0, stream>>>(x, xb, stats_mc, N * H_IN / 4, H_IN);

    // 4 layers; layer 0 reads xb (K=256), layers 1..3 read ACTb (K=128)
    for (int l = 0; l < 4; ++l) {
        const u16* Ab     = (l == 0) ? xb : ACTb;
        int K             = (l == 0) ? H_IN : H;
        const float* W    = (l == 0) ? Wfeat : Ws + (size_t)(l - 1) * H * H;
        const float* bias = (l == 0) ? bfeat : bs + (size_t)(l - 1) * H;
        const float* g    = (l == 0) ? bnfg : bng + (size_t)(l - 1) * H;
        const float* bb   = (l == 0) ? bnfb : bnb + (size_t)(l - 1) * H;
        int do_stats      = (l < 3);

        fold_k<<<H, K, 0, stream>>>(W, stats_mc, g, bb, bias, Wt, bp, N, K);
        float* sz = do_stats ? stats_mc : nullptr;   // gemm block 0 zeroes for csragg
        if (l == 0) gemm_mfma_k<8><<<512, 256, 0, stream>>>(Ab, Wt, Yb, N, sz);
        else        gemm_mfma_k<4><<<512, 256, 0, stream>>>(Ab, Wt, Yb, N, sz);
        csragg_k<<<(N + 15) / 16, 256, 0, stream>>>(rowptr, esrc, Yb, dinv, bp,
                                                    ACTb, (l == 3) ? out : nullptr,
                                                    stats_mc, do_stats, N);
    }
}